// Round 1
// 80.737 us; speedup vs baseline: 1.0322x; 1.0322x over previous
//
#include <hip/hip_runtime.h>
#include <hip/hip_fp16.h>
#include <stdint.h>

// out[c,b,g] = sum_{s<8} prod_{l<3} x[b, I[c,g,s,l]]
#define Cc 16
#define Gg 8192
#define Ss 8
#define Ll 3
#define Bb 32

#define ZS 4               // b-oct slices (f16): slice z holds b = 8z .. 8z+7
#define THREADS 1024
#define ITERS 2            // (c,g) per thread per block

// Evaluate one (c,g): 24 indices in q[6], gathers from the swizzled LDS image.
// Processed in two 12-index half-batches to cap live VGPRs (48 gather regs,
// not 96) -- required to fit the 128-VGPR budget of a 1024-thread block.
__device__ __forceinline__ void clause_eval(const uint2* __restrict__ xl2,
                                            const int4 q[6], float acc[8]) {
    #pragma unroll
    for (int h = 0; h < 2; ++h) {
        const int4 qa = q[3 * h + 0];
        const int4 qb = q[3 * h + 1];
        const int4 qc = q[3 * h + 2];
        int idx[12] = {qa.x, qa.y, qa.z, qa.w,
                       qb.x, qb.y, qb.z, qb.w,
                       qc.x, qc.y, qc.z, qc.w};
        uint2 r0[12], r1[12];
        #pragma unroll
        for (int k = 0; k < 12; ++k) {           // 24 independent ds_read_b64
            uint32_t u = (uint32_t)idx[k];
            uint32_t a0 = (u << 1) | ((u >> 3) & 1u);  // undo build-side swap
            r0[k] = xl2[a0];                     // b 0..3 (f16 pairs)
            r1[k] = xl2[a0 ^ 1u];                // b 4..7
        }
        #pragma unroll
        for (int s = 0; s < 4; ++s) {
            const int k0 = 3 * s, k1 = 3 * s + 1, k2 = 3 * s + 2;
            const uint32_t pa[4] = {r0[k0].x, r0[k0].y, r1[k0].x, r1[k0].y};
            const uint32_t pb[4] = {r0[k1].x, r0[k1].y, r1[k1].x, r1[k1].y};
            const uint32_t pd[4] = {r0[k2].x, r0[k2].y, r1[k2].x, r1[k2].y};
            #pragma unroll
            for (int j = 0; j < 4; ++j) {
                __half2 a = *(const __half2*)&pa[j];
                __half2 b = *(const __half2*)&pb[j];
                __half2 d = *(const __half2*)&pd[j];
                __half2 p = __hmul2(__hmul2(a, b), d);   // v_pk_mul_f16 x2
                float2 pf = __half22float2(p);
                acc[2 * j]     += pf.x;
                acc[2 * j + 1] += pf.y;
            }
        }
    }
}

// Fused single kernel:
//  - 256 blocks x 1024 threads = exactly 1 block/CU, 16 waves/CU (4/SIMD),
//    ONE block-round (previous version: 512 blocks = 2 sequential rounds at
//    2 waves/SIMD).
//  - f16 build is inlined into staging: read x f32 straight from L2 (x = 1 MB,
//    L2-resident), convert in-register, ds_write_b128 lane-stride-16B
//    (conflict-free). No build_xh kernel, no workspace, no xh round-trip.
//  - XCD-bijective swizzle co-locates the 4 z-twin blocks (same c,g-range,
//    different z) on one XCD so their identical I reads hit the same L2.
__global__ __launch_bounds__(THREADS, 4) void clause_f16_fused(
        const float* __restrict__ x, const int* __restrict__ I,
        float* __restrict__ out) {
    __shared__ uint4 xl[Gg];                       // 128 KB
    const int tid = threadIdx.x;

    // 256 blocks, 8 XCDs, 32 blocks/XCD. Bijective: (bx&7)*32 + (bx>>3).
    // XCD x gets logical blocks 32x..32x+31, which contain all 4 z-twins of
    // each (c, g-chunk) -> I re-reads are L2 hits.
    const int lb = (blockIdx.x & 7) * 32 + (blockIdx.x >> 3);
    const int c = lb >> 4;                         // 16 logical blocks per c
    const int z = (lb >> 2) & 3;
    const int gbase = (lb & 3) * (THREADS * ITERS);

    // Prefetch both iterations' raw int32 indices early (HBM latency hides
    // under the L2 staging phase).
    const int g0 = gbase + tid;
    const int g1 = gbase + THREADS + tid;
    const int4* ip0 = (const int4*)(I + ((size_t)c * Gg + g0) * (Ss * Ll));
    const int4* ip1 = (const int4*)(I + ((size_t)c * Gg + g1) * (Ss * Ll));
    int4 q0[6], q1[6];
    #pragma unroll
    for (int k = 0; k < 6; ++k) q0[k] = ip0[k];
    #pragma unroll
    for (int k = 0; k < 6; ++k) q1[k] = ip1[k];

    // Stage slice z with inline f32->f16 build.
    // Thread t owns g = t + k*1024: loads are per-b coalesced dword streams,
    // ds_write_b128 at lane-stride 16 B = full-bandwidth pattern.
    // Two 8B halves SWAPPED when (g>>3)&1 (R8 swizzle; reader undoes it in
    // the address) to spread gather start-banks over 16 slots instead of 8.
    {
        const float* xs = x + (size_t)(8 * z) * Gg;
        #pragma unroll 4                           // cap in-flight regs
        for (int k = 0; k < 8; ++k) {
            const int g = tid + k * THREADS;
            float v[8];
            #pragma unroll
            for (int b = 0; b < 8; ++b) v[b] = xs[(size_t)b * Gg + g];
            uint32_t d[4];
            #pragma unroll
            for (int j = 0; j < 4; ++j) {
                __half2 h = __floats2half2_rn(v[2 * j], v[2 * j + 1]);
                d[j] = *(const uint32_t*)&h;
            }
            const uint32_t s = (g >> 3) & 1u;
            xl[g] = s ? make_uint4(d[2], d[3], d[0], d[1])
                      : make_uint4(d[0], d[1], d[2], d[3]);
        }
    }

    __syncthreads();                               // the ONE barrier

    const uint2* xl2 = (const uint2*)xl;
    float* opb = out + ((size_t)(c * Bb + 8 * z)) * Gg;

    {
        float acc[8] = {0, 0, 0, 0, 0, 0, 0, 0};
        clause_eval(xl2, q0, acc);
        #pragma unroll
        for (int j = 0; j < 8; ++j)                // lane-consecutive g -> coalesced
            opb[(size_t)j * Gg + g0] = acc[j];
    }
    {
        float acc[8] = {0, 0, 0, 0, 0, 0, 0, 0};
        clause_eval(xl2, q1, acc);
        #pragma unroll
        for (int j = 0; j < 8; ++j)
            opb[(size_t)j * Gg + g1] = acc[j];
    }
}

extern "C" void kernel_launch(void* const* d_in, const int* in_sizes, int n_in,
                              void* d_out, int out_size, void* d_ws, size_t ws_size,
                              hipStream_t stream) {
    const float* x = (const float*)d_in[0];
    const int* I = (const int*)d_in[1];
    float* out = (float*)d_out;
    (void)d_ws; (void)ws_size;                     // workspace no longer needed

    const int grid = (Cc * Gg * ZS) / (THREADS * ITERS);   // 256 blocks
    clause_f16_fused<<<grid, THREADS, 0, stream>>>(x, I, out);
}